// Round 1
// baseline (5302.130 us; speedup 1.0000x reference)
//
#include <hip/hip_runtime.h>
#include <hip/hip_bf16.h>
#include <math.h>

// Problem dims
#define B_  32
#define T_  512
#define D_  128
#define N_  1024
#define NOISE_ 0.001f

#define NBLK 64           // recurrence blocks; each owns N_/NBLK = 16 columns
#define CPB  16           // columns per block

typedef __attribute__((ext_vector_type(8))) short  bf16x8;
typedef __attribute__((ext_vector_type(4))) float  f32x4;

static __device__ __forceinline__ unsigned short f2bf_rn(float f) {
    unsigned int u = __builtin_bit_cast(unsigned int, f);
    unsigned int r = (u + 0x7FFFu + ((u >> 16) & 1u)) >> 16;
    return (unsigned short)r;
}
static __device__ __forceinline__ float bf2f(unsigned short h) {
    return __builtin_bit_cast(float, (unsigned int)h << 16);
}

// ---------------------------------------------------------------------------
// Kernel A: xin = (x @ w_input) * scale, written INTO d_out at [b][t][n].
// M = B_*T_ = 16384 rows (row = b*512+t, contiguous in x), K=128, N=1024.
// fp32, LDS-tiled 64x64, full-K staging, 4x4 per thread.
// ---------------------------------------------------------------------------
__global__ __launch_bounds__(256) void xin_gemm(
    const float* __restrict__ x, const float* __restrict__ w_in,
    const float* __restrict__ scale_p, float* __restrict__ out) {
  __shared__ float As[64 * 132];   // pad 132 (528 B rows, 16B-aligned)
  __shared__ float Bs[128 * 68];   // pad 68  (272 B rows, 16B-aligned)
  const int tid = threadIdx.x;
  const int bm = blockIdx.x;       // 0..255
  const int bn = blockIdx.y;       // 0..15

  // A tile: 64 rows x 128 cols = 2048 float4
  {
    const f32x4* xg = (const f32x4*)(x + (size_t)bm * 64 * 128);
#pragma unroll
    for (int i = 0; i < 8; ++i) {
      int idx = tid + i * 256;          // 0..2047
      int r = idx >> 5, c4 = idx & 31;  // 32 float4 per row
      f32x4 v = xg[idx];
      float* dst = &As[r * 132 + c4 * 4];
      dst[0] = v.x; dst[1] = v.y; dst[2] = v.z; dst[3] = v.w;
    }
  }
  // B tile: 128 rows x 64 cols = 2048 float4
  {
#pragma unroll
    for (int i = 0; i < 8; ++i) {
      int idx = tid + i * 256;
      int r = idx >> 4, c4 = idx & 15;  // 16 float4 per row
      f32x4 v = *(const f32x4*)(w_in + (size_t)r * N_ + bn * 64 + c4 * 4);
      float* dst = &Bs[r * 68 + c4 * 4];
      dst[0] = v.x; dst[1] = v.y; dst[2] = v.z; dst[3] = v.w;
    }
  }
  __syncthreads();

  const int tx = tid & 15, ty = tid >> 4;
  float acc[4][4] = {};
  for (int k = 0; k < 128; ++k) {
    float a0 = As[(ty * 4 + 0) * 132 + k];
    float a1 = As[(ty * 4 + 1) * 132 + k];
    float a2 = As[(ty * 4 + 2) * 132 + k];
    float a3 = As[(ty * 4 + 3) * 132 + k];
    f32x4 bv = *(const f32x4*)&Bs[k * 68 + tx * 4];
#pragma unroll
    for (int j = 0; j < 4; ++j) {
      acc[0][j] += a0 * bv[j];
      acc[1][j] += a1 * bv[j];
      acc[2][j] += a2 * bv[j];
      acc[3][j] += a3 * bv[j];
    }
  }
  const float s = scale_p[0];
#pragma unroll
  for (int i = 0; i < 4; ++i) {
    int row = bm * 64 + ty * 4 + i;        // = b*512 + t
    if ((row & 511) == 0) continue;        // t==0 slot handled by init kernel
    f32x4 o;
    o.x = acc[i][0] * s; o.y = acc[i][1] * s;
    o.z = acc[i][2] * s; o.w = acc[i][3] * s;
    *(f32x4*)(out + (size_t)row * N_ + bn * 64 + tx * 4) = o;
  }
}

// ---------------------------------------------------------------------------
// Kernel B: out[:,0,:] = step0 ; states0 -> compensated bf16 ping buffer 0 ;
// zero barrier flags.
// ---------------------------------------------------------------------------
__global__ __launch_bounds__(256) void init_k(
    const float* __restrict__ states0, const float* __restrict__ step0,
    float* __restrict__ out, unsigned short* __restrict__ st_hi,
    unsigned short* __restrict__ st_lo, int* __restrict__ flags) {
  int i = blockIdx.x * 256 + threadIdx.x;   // grid 128 blocks -> 32768
  if (i < B_ * N_) {
    int b = i >> 10, n = i & 1023;
    out[((size_t)b * T_ + 0) * N_ + n] = step0[i];
    float sv = states0[i];
    unsigned short h = f2bf_rn(sv);
    st_hi[i] = h;
    st_lo[i] = f2bf_rn(sv - bf2f(h));
  }
  if (i < 1024) flags[i] = 0;
}

// ---------------------------------------------------------------------------
// Kernel C: persistent recurrence. 64 blocks x 256 threads.
// Block owns columns [blk*16, blk*16+16). w_res slice resident in LDS as
// compensated bf16 (hi+lo). Each wave covers K-chunk of 256 with
// mfma_f32_16x16x32_bf16; partials reduced in LDS; tanh+noise; bf16 hi/lo
// states published to global ping-pong; device-scope barrier per step.
// ---------------------------------------------------------------------------
__global__ __launch_bounds__(256) void esn_rec(
    const float* __restrict__ w_res, const float* __restrict__ rn,
    float* __restrict__ out, unsigned short* __restrict__ st_hi,
    unsigned short* __restrict__ st_lo, int* flags) {
  // LDS: w slices as short8-rows of 129 (=1032 shorts, 2064 B stride -> 16B
  // aligned, uniform bank distribution for b128 reads)
  __shared__ bf16x8 wHi8[CPB * 129];
  __shared__ bf16x8 wLo8[CPB * 129];
  __shared__ float  pLDS[4 * 32 * 17];   // [wave][m(32)][c(16)] pad 17

  const int tid = threadIdx.x;
  const int blk = blockIdx.x;

  // one-time: load + split w_res column slice
  {
    unsigned short* wH = (unsigned short*)wHi8;
    unsigned short* wL = (unsigned short*)wLo8;
    for (int i = tid; i < CPB * 1024; i += 256) {
      int c = i & 15, k = i >> 4;
      float wv = w_res[(size_t)k * N_ + blk * CPB + c];
      unsigned short h = f2bf_rn(wv);
      wH[c * 1032 + k] = h;
      wL[c * 1032 + k] = f2bf_rn(wv - bf2f(h));
    }
  }
  __syncthreads();

  const int lane = tid & 63, wave = tid >> 6;
  const int quad = lane >> 4, lm = lane & 15;
  const int kc8 = (wave * 256) >> 3;     // wave's K-chunk base, short8 units

  // reduce-phase constants (each thread owns (rm,rc) and (rm+16,rc))
  const int rm = tid >> 4;               // 0..15
  const int rc = tid & 15;
  const int colg = blk * CPB + rc;
  const float nz0 = NOISE_ * rn[(size_t)rm * N_ + colg];
  const float nz1 = NOISE_ * rn[(size_t)(rm + 16) * N_ + colg];

  for (int t = 1; t < T_; ++t) {
    const int pc = (t - 1) & 1, ncur = t & 1;
    const bf16x8* sh8 = (const bf16x8*)(st_hi + pc * (B_ * N_));
    const bf16x8* sl8 = (const bf16x8*)(st_lo + pc * (B_ * N_));

    f32x4 acc0 = {0.f, 0.f, 0.f, 0.f};
    f32x4 acc1 = {0.f, 0.f, 0.f, 0.f};
#pragma unroll
    for (int kk = 0; kk < 8; ++kk) {
      const int k8 = kc8 + kk * 4 + quad;           // short8 index along K
      bf16x8 ah0 = sh8[lm * 128 + k8];              // A[m=lm][k..k+7], batches 0..15
      bf16x8 ah1 = sh8[(lm + 16) * 128 + k8];       // batches 16..31
      bf16x8 al0 = sl8[lm * 128 + k8];
      bf16x8 al1 = sl8[(lm + 16) * 128 + k8];
      bf16x8 bh  = wHi8[lm * 129 + k8];             // B[k][n=lm]
      bf16x8 bl  = wLo8[lm * 129 + k8];
      acc0 = __builtin_amdgcn_mfma_f32_16x16x32_bf16(ah0, bh, acc0, 0, 0, 0);
      acc1 = __builtin_amdgcn_mfma_f32_16x16x32_bf16(ah1, bh, acc1, 0, 0, 0);
      acc0 = __builtin_amdgcn_mfma_f32_16x16x32_bf16(al0, bh, acc0, 0, 0, 0);
      acc1 = __builtin_amdgcn_mfma_f32_16x16x32_bf16(al1, bh, acc1, 0, 0, 0);
      acc0 = __builtin_amdgcn_mfma_f32_16x16x32_bf16(ah0, bl, acc0, 0, 0, 0);
      acc1 = __builtin_amdgcn_mfma_f32_16x16x32_bf16(ah1, bl, acc1, 0, 0, 0);
    }

    // write K-partials: C frag layout row=quad*4+r, col=lm
#pragma unroll
    for (int r = 0; r < 4; ++r) {
      pLDS[wave * 544 + (quad * 4 + r) * 17 + lm]        = acc0[r];
      pLDS[wave * 544 + (quad * 4 + r + 16) * 17 + lm]   = acc1[r];
    }
    __syncthreads();

    // reduce 4 K-partials, + xin (preloaded in out), tanh, + noise
    float s0 = pLDS[0 * 544 + rm * 17 + rc] + pLDS[1 * 544 + rm * 17 + rc]
             + pLDS[2 * 544 + rm * 17 + rc] + pLDS[3 * 544 + rm * 17 + rc];
    float s1 = pLDS[0 * 544 + (rm + 16) * 17 + rc] + pLDS[1 * 544 + (rm + 16) * 17 + rc]
             + pLDS[2 * 544 + (rm + 16) * 17 + rc] + pLDS[3 * 544 + (rm + 16) * 17 + rc];
    size_t o0 = ((size_t)rm * T_ + t) * N_ + colg;
    size_t o1 = ((size_t)(rm + 16) * T_ + t) * N_ + colg;
    float v0 = tanhf(s0 + out[o0]) + nz0;
    float v1 = tanhf(s1 + out[o1]) + nz1;
    out[o0] = v0;
    out[o1] = v1;
    unsigned short h0 = f2bf_rn(v0), h1 = f2bf_rn(v1);
    unsigned short* dh = st_hi + ncur * (B_ * N_);
    unsigned short* dl = st_lo + ncur * (B_ * N_);
    dh[(size_t)rm * N_ + colg] = h0;
    dl[(size_t)rm * N_ + colg] = f2bf_rn(v0 - bf2f(h0));
    dh[(size_t)(rm + 16) * N_ + colg] = h1;
    dl[(size_t)(rm + 16) * N_ + colg] = f2bf_rn(v1 - bf2f(h1));

    // ---- device-scope barrier ----
    __builtin_amdgcn_fence(__ATOMIC_RELEASE, "workgroup");  // drain this thread's stores
    __syncthreads();
    if (tid == 0) {
      __builtin_amdgcn_fence(__ATOMIC_SEQ_CST, "agent");    // wbl2: publish block's stores
      __hip_atomic_fetch_add(&flags[t], 1, __ATOMIC_RELAXED, __HIP_MEMORY_SCOPE_AGENT);
      while (__hip_atomic_load(&flags[t], __ATOMIC_RELAXED, __HIP_MEMORY_SCOPE_AGENT) < NBLK)
        __builtin_amdgcn_s_sleep(2);
      __builtin_amdgcn_fence(__ATOMIC_ACQUIRE, "agent");    // inv L1+L2 before reading states
    }
    __syncthreads();
  }
}

// ---------------------------------------------------------------------------
extern "C" void kernel_launch(void* const* d_in, const int* in_sizes, int n_in,
                              void* d_out, int out_size, void* d_ws, size_t ws_size,
                              hipStream_t stream) {
  const float* x       = (const float*)d_in[0];
  const float* w_in    = (const float*)d_in[1];
  const float* w_res   = (const float*)d_in[2];
  const float* wscale  = (const float*)d_in[3];
  const float* states0 = (const float*)d_in[4];
  const float* step0   = (const float*)d_in[5];
  const float* rnoise  = (const float*)d_in[6];
  float* out = (float*)d_out;

  char* ws = (char*)d_ws;
  unsigned short* st_hi = (unsigned short*)ws;                 // 2*32*1024*2 = 131072 B
  unsigned short* st_lo = (unsigned short*)(ws + 131072);      // 131072 B
  int* flags            = (int*)(ws + 262144);                 // 4096 B

  // xin -> out (t>=1 slots)
  xin_gemm<<<dim3(256, 16), 256, 0, stream>>>(x, w_in, wscale, out);
  // t=0 slice, initial states (compensated bf16), zero flags
  init_k<<<128, 256, 0, stream>>>(states0, step0, out, st_hi, st_lo, flags);
  // persistent recurrence
  esn_rec<<<NBLK, 256, 0, stream>>>(w_res, rnoise, out, st_hi, st_lo, flags);
}

// Round 2
// 3908.849 us; speedup vs baseline: 1.3564x; 1.3564x over previous
//
#include <hip/hip_runtime.h>
#include <hip/hip_bf16.h>
#include <math.h>

// Problem dims
#define B_  32
#define T_  512
#define D_  128
#define N_  1024
#define NOISE_ 0.001f

#define NBLK 64           // recurrence blocks; each owns N_/NBLK = 16 columns
#define CPB  16           // columns per block

typedef __attribute__((ext_vector_type(8))) short  bf16x8;
typedef __attribute__((ext_vector_type(4))) float  f32x4;

static __device__ __forceinline__ unsigned short f2bf_rn(float f) {
    unsigned int u = __builtin_bit_cast(unsigned int, f);
    unsigned int r = (u + 0x7FFFu + ((u >> 16) & 1u)) >> 16;
    return (unsigned short)r;
}
static __device__ __forceinline__ float bf2f(unsigned short h) {
    return __builtin_bit_cast(float, (unsigned int)h << 16);
}

// ---------------------------------------------------------------------------
// Kernel A: xin = (x @ w_input) * scale, written INTO d_out at [b][t][n].
// ---------------------------------------------------------------------------
__global__ __launch_bounds__(256) void xin_gemm(
    const float* __restrict__ x, const float* __restrict__ w_in,
    const float* __restrict__ scale_p, float* __restrict__ out) {
  __shared__ float As[64 * 132];
  __shared__ float Bs[128 * 68];
  const int tid = threadIdx.x;
  const int bm = blockIdx.x;       // 0..255
  const int bn = blockIdx.y;       // 0..15

  {
    const f32x4* xg = (const f32x4*)(x + (size_t)bm * 64 * 128);
#pragma unroll
    for (int i = 0; i < 8; ++i) {
      int idx = tid + i * 256;
      int r = idx >> 5, c4 = idx & 31;
      f32x4 v = xg[idx];
      float* dst = &As[r * 132 + c4 * 4];
      dst[0] = v.x; dst[1] = v.y; dst[2] = v.z; dst[3] = v.w;
    }
  }
  {
#pragma unroll
    for (int i = 0; i < 8; ++i) {
      int idx = tid + i * 256;
      int r = idx >> 4, c4 = idx & 15;
      f32x4 v = *(const f32x4*)(w_in + (size_t)r * N_ + bn * 64 + c4 * 4);
      float* dst = &Bs[r * 68 + c4 * 4];
      dst[0] = v.x; dst[1] = v.y; dst[2] = v.z; dst[3] = v.w;
    }
  }
  __syncthreads();

  const int tx = tid & 15, ty = tid >> 4;
  float acc[4][4] = {};
  for (int k = 0; k < 128; ++k) {
    float a0 = As[(ty * 4 + 0) * 132 + k];
    float a1 = As[(ty * 4 + 1) * 132 + k];
    float a2 = As[(ty * 4 + 2) * 132 + k];
    float a3 = As[(ty * 4 + 3) * 132 + k];
    f32x4 bv = *(const f32x4*)&Bs[k * 68 + tx * 4];
#pragma unroll
    for (int j = 0; j < 4; ++j) {
      acc[0][j] += a0 * bv[j];
      acc[1][j] += a1 * bv[j];
      acc[2][j] += a2 * bv[j];
      acc[3][j] += a3 * bv[j];
    }
  }
  const float s = scale_p[0];
#pragma unroll
  for (int i = 0; i < 4; ++i) {
    int row = bm * 64 + ty * 4 + i;
    if ((row & 511) == 0) continue;
    f32x4 o;
    o.x = acc[i][0] * s; o.y = acc[i][1] * s;
    o.z = acc[i][2] * s; o.w = acc[i][3] * s;
    *(f32x4*)(out + (size_t)row * N_ + bn * 64 + tx * 4) = o;
  }
}

// ---------------------------------------------------------------------------
// Kernel B: out[:,0,:] = step0 ; states0 -> compensated bf16 ping buffer 0 ;
// zero per-block flags.
// ---------------------------------------------------------------------------
__global__ __launch_bounds__(256) void init_k(
    const float* __restrict__ states0, const float* __restrict__ step0,
    float* __restrict__ out, unsigned short* __restrict__ st_hi,
    unsigned short* __restrict__ st_lo, int* __restrict__ flags) {
  int i = blockIdx.x * 256 + threadIdx.x;
  if (i < B_ * N_) {
    int b = i >> 10, n = i & 1023;
    out[((size_t)b * T_ + 0) * N_ + n] = step0[i];
    float sv = states0[i];
    unsigned short h = f2bf_rn(sv);
    st_hi[i] = h;
    st_lo[i] = f2bf_rn(sv - bf2f(h));
  }
  if (i < 1024) flags[i] = 0;   // 64 flags at 16-int (64 B) stride
}

// ---------------------------------------------------------------------------
// Kernel C: persistent recurrence. 64 blocks x 256 threads.
// Publish states via system-scope write-through stores (no wbl2 needed);
// per-block monotone flag (value = t) + parallel 64-lane poll (no atomic RMW);
// one acquire/buffer_inv per step so state loads stay plain dwordx4.
// ---------------------------------------------------------------------------
__global__ __launch_bounds__(256) void esn_rec(
    const float* __restrict__ w_res, const float* __restrict__ rn,
    float* __restrict__ out, unsigned short* __restrict__ st_hi,
    unsigned short* __restrict__ st_lo, int* flags) {
  __shared__ bf16x8 wHi8[CPB * 129];
  __shared__ bf16x8 wLo8[CPB * 129];
  __shared__ float  pLDS[4 * 32 * 17];   // [wave][m(32)][c(16)] pad 17

  const int tid = threadIdx.x;
  const int blk = blockIdx.x;

  // one-time: load + split w_res column slice into LDS (compensated bf16)
  {
    unsigned short* wH = (unsigned short*)wHi8;
    unsigned short* wL = (unsigned short*)wLo8;
    for (int i = tid; i < CPB * 1024; i += 256) {
      int c = i & 15, k = i >> 4;
      float wv = w_res[(size_t)k * N_ + blk * CPB + c];
      unsigned short h = f2bf_rn(wv);
      wH[c * 1032 + k] = h;
      wL[c * 1032 + k] = f2bf_rn(wv - bf2f(h));
    }
  }
  __syncthreads();

  const int lane = tid & 63, wave = tid >> 6;
  const int quad = lane >> 4, lm = lane & 15;
  const int kc8 = wave * 32;             // wave's K-chunk base, short8 units

  // epilogue mapping: thread owns (row rm, cols cp, cp+1)
  const int rm = tid >> 3;               // 0..31
  const int cp = (tid & 7) * 2;          // 0,2,..,14
  const int colg = blk * CPB + cp;
  float2 nz = *(const float2*)&rn[(size_t)rm * N_ + colg];
  nz.x *= NOISE_; nz.y *= NOISE_;

  for (int t = 1; t < T_; ++t) {
    const int pc = (t - 1) & 1, ncur = t & 1;

    // prefetch xin (own address; written by xin_gemm, read+overwritten by us)
    size_t o0 = ((size_t)rm * T_ + t) * N_ + colg;
    float2 xv = *(const float2*)&out[o0];

    if (t > 1) {
      if (wave == 0) {
        const int need = t - 1;
        while (true) {
          int v = __hip_atomic_load(&flags[lane * 16], __ATOMIC_RELAXED,
                                    __HIP_MEMORY_SCOPE_SYSTEM);
          if (__all(v >= need)) break;
        }
      }
      __syncthreads();
      __builtin_amdgcn_fence(__ATOMIC_ACQUIRE, "agent");   // buffer_inv
    }

    const bf16x8* sh8 = (const bf16x8*)(st_hi + pc * (B_ * N_));
    const bf16x8* sl8 = (const bf16x8*)(st_lo + pc * (B_ * N_));

    f32x4 acc0 = {0.f, 0.f, 0.f, 0.f};
    f32x4 acc1 = {0.f, 0.f, 0.f, 0.f};
#pragma unroll
    for (int kk = 0; kk < 8; ++kk) {
      const int k8 = kc8 + kk * 4 + quad;
      bf16x8 ah0 = sh8[lm * 128 + k8];
      bf16x8 ah1 = sh8[(lm + 16) * 128 + k8];
      bf16x8 al0 = sl8[lm * 128 + k8];
      bf16x8 al1 = sl8[(lm + 16) * 128 + k8];
      bf16x8 bh  = wHi8[lm * 129 + k8];
      bf16x8 bl  = wLo8[lm * 129 + k8];
      acc0 = __builtin_amdgcn_mfma_f32_16x16x32_bf16(ah0, bh, acc0, 0, 0, 0);
      acc1 = __builtin_amdgcn_mfma_f32_16x16x32_bf16(ah1, bh, acc1, 0, 0, 0);
      acc0 = __builtin_amdgcn_mfma_f32_16x16x32_bf16(al0, bh, acc0, 0, 0, 0);
      acc1 = __builtin_amdgcn_mfma_f32_16x16x32_bf16(al1, bh, acc1, 0, 0, 0);
      acc0 = __builtin_amdgcn_mfma_f32_16x16x32_bf16(ah0, bl, acc0, 0, 0, 0);
      acc1 = __builtin_amdgcn_mfma_f32_16x16x32_bf16(ah1, bl, acc1, 0, 0, 0);
    }

    // write K-partials: C frag layout row=quad*4+r, col=lm
#pragma unroll
    for (int r = 0; r < 4; ++r) {
      pLDS[wave * 544 + (quad * 4 + r) * 17 + lm]      = acc0[r];
      pLDS[wave * 544 + (quad * 4 + r + 16) * 17 + lm] = acc1[r];
    }
    __syncthreads();

    // reduce 4 K-partials for (rm, cp) and (rm, cp+1)
    float sa = pLDS[0 * 544 + rm * 17 + cp] + pLDS[1 * 544 + rm * 17 + cp]
             + pLDS[2 * 544 + rm * 17 + cp] + pLDS[3 * 544 + rm * 17 + cp];
    float sb = pLDS[0 * 544 + rm * 17 + cp + 1] + pLDS[1 * 544 + rm * 17 + cp + 1]
             + pLDS[2 * 544 + rm * 17 + cp + 1] + pLDS[3 * 544 + rm * 17 + cp + 1];
    float v0 = tanhf(sa + xv.x) + nz.x;
    float v1 = tanhf(sb + xv.y) + nz.y;
    float2 ov; ov.x = v0; ov.y = v1;
    *(float2*)&out[o0] = ov;

    // publish compensated bf16 state: write-through system stores (no wbl2)
    unsigned short h0 = f2bf_rn(v0), h1 = f2bf_rn(v1);
    unsigned short l0 = f2bf_rn(v0 - bf2f(h0)), l1 = f2bf_rn(v1 - bf2f(h1));
    unsigned int hpack = (unsigned int)h0 | ((unsigned int)h1 << 16);
    unsigned int lpack = (unsigned int)l0 | ((unsigned int)l1 << 16);
    unsigned int* dh = (unsigned int*)(st_hi + ncur * (B_ * N_) + (size_t)rm * N_ + colg);
    unsigned int* dl = (unsigned int*)(st_lo + ncur * (B_ * N_) + (size_t)rm * N_ + colg);
    __hip_atomic_store(dh, hpack, __ATOMIC_RELAXED, __HIP_MEMORY_SCOPE_SYSTEM);
    __hip_atomic_store(dl, lpack, __ATOMIC_RELAXED, __HIP_MEMORY_SCOPE_SYSTEM);

    __syncthreads();   // drains each thread's vmcnt (release for sc stores)
    if (tid == 0) {
      __hip_atomic_store(&flags[blk * 16], t, __ATOMIC_RELAXED,
                         __HIP_MEMORY_SCOPE_SYSTEM);
    }
  }
}

// ---------------------------------------------------------------------------
extern "C" void kernel_launch(void* const* d_in, const int* in_sizes, int n_in,
                              void* d_out, int out_size, void* d_ws, size_t ws_size,
                              hipStream_t stream) {
  const float* x       = (const float*)d_in[0];
  const float* w_in    = (const float*)d_in[1];
  const float* w_res   = (const float*)d_in[2];
  const float* wscale  = (const float*)d_in[3];
  const float* states0 = (const float*)d_in[4];
  const float* step0   = (const float*)d_in[5];
  const float* rnoise  = (const float*)d_in[6];
  float* out = (float*)d_out;

  char* ws = (char*)d_ws;
  unsigned short* st_hi = (unsigned short*)ws;                 // 131072 B
  unsigned short* st_lo = (unsigned short*)(ws + 131072);      // 131072 B
  int* flags            = (int*)(ws + 262144);                 // 4096 B

  xin_gemm<<<dim3(256, 16), 256, 0, stream>>>(x, w_in, wscale, out);
  init_k<<<128, 256, 0, stream>>>(states0, step0, out, st_hi, st_lo, flags);
  esn_rec<<<NBLK, 256, 0, stream>>>(w_res, rnoise, out, st_hi, st_lo, flags);
}